// Round 12
// baseline (500.793 us; speedup 1.0000x reference)
//
#include <hip/hip_runtime.h>
#include <stdint.h>

#define NN 64
#define CC 128
#define TT 300
#define VV 25
#define TV 7500
#define DD 256
#define RR 32
#define JPAD 7552   // padded row stride for yT and z (59*128)
#define JT 125      // shift kernel j-tile (exactly 5 t-columns)
#define NJT 60
#define CBL 32      // c per shift block

// ws float offsets
#define OFF_S1P    0          // [c][64] partial x sums
#define OFF_SS1P   8192       // [c][64] partial x sumsq
#define OFF_PS     16384      // [n][c] xs sums
#define OFF_SUM2   24832
#define OFF_SUMSQ2 25088
#define OFF_GATE   25856
#define OFF_BIAS2  26112      // [n][d]
#define OFF_CORR0  42496      // [n][d]
#define OFF_CORR9  58880      // [n][d]
#define FLOAT_REGION 75264
#define ZERO_CNT   25344
#define WT_BYTE_OFF ((size_t)FLOAT_REGION * 4)
#define WT_BYTES    ((size_t)NN * DD * CC * 2)
#define Z_BYTE_OFF  (WT_BYTE_OFF + WT_BYTES)

typedef __attribute__((ext_vector_type(8))) short short8;
typedef __attribute__((ext_vector_type(4))) float f32x4;

typedef const __attribute__((address_space(1))) uint32_t gas_u32;
typedef __attribute__((address_space(3))) uint32_t las_u32;

__device__ inline ushort f2bf(float f) {
    uint32_t u = __float_as_uint(f);
    u += 0x7fffu + ((u >> 16) & 1u);
    return (ushort)(u >> 16);
}
__device__ inline float bf2f(ushort v) { return __uint_as_float(((uint32_t)v) << 16); }
__device__ inline void async_copy16(const void* g, void* l) {
    __builtin_amdgcn_global_load_lds((gas_u32*)g, (las_u32*)l, 16, 0, 0);
}

__device__ inline void block_reduce2(float& a, float& b) {
    __shared__ float sa[4], sb[4];
    for (int off = 32; off > 0; off >>= 1) {
        a += __shfl_down(a, off);
        b += __shfl_down(b, off);
    }
    int lane = threadIdx.x & 63, wid = threadIdx.x >> 6;
    if (lane == 0) { sa[wid] = a; sb[wid] = b; }
    __syncthreads();
    if (threadIdx.x == 0) {
        a = sa[0] + sa[1] + sa[2] + sa[3];
        b = sb[0] + sb[1] + sb[2] + sb[3];
    }
}

__global__ void k_zero(float* ws) {
    int i = blockIdx.x * 256 + threadIdx.x;
    for (; i < ZERO_CNT; i += 32 * 256) ws[i] = 0.f;
}

// Shift+stats v4: direct 2-stream global reads (tap + ±25 neighbor share cache
// lines), no x LDS window; 8KB LDS (ytile only) -> 8 blocks/CU. grid (60,4,64).
__global__ __launch_bounds__(256) void k_shift_stats(const float* __restrict__ x,
                                                     const float* __restrict__ shift_in,
                                                     float* __restrict__ ws,
                                                     ushort* __restrict__ yT) {
    __shared__ ushort ytile[CBL * 128];   // 8192 B
    int jt = blockIdx.x, ch = blockIdx.y, n = blockIdx.z;
    int j0 = jt * JT;
    int tid = threadIdx.x;
    int k = tid & 7;        // j-chunk of 16 within tile
    int cl = tid >> 3;      // local c 0..31
    int c = ch * CBL + cl;
    float sh = shift_in[c];
    bool posi = (sh >= 0.f);
    float asv = fabsf(sh);
    float wt = 1.f - asv;
    int off = posi ? VV : -VV;
    const float* px = x + ((size_t)n * CC + c) * TV;
    bool eLo = (jt == 0) && !posi;
    bool eHi = (jt == NJT - 1) && posi;
    int key = (cl & 7) ^ ((cl >> 3) & 7);
    int jb = j0 + k * 16;
    int nbase = jb + off;

    float4 t0, t1, t2, t3, nb0, nb1, nb2, nb3;
#define ICLAMP(i) min(max((i), 0), TV - 1)
#define LD4C(dst, base)                                        \
    dst.x = px[ICLAMP((base) + 0)]; dst.y = px[ICLAMP((base) + 1)]; \
    dst.z = px[ICLAMP((base) + 2)]; dst.w = px[ICLAMP((base) + 3)];
    if (jb + 15 < TV) {
        t0 = *(const float4*)(px + jb);
        t1 = *(const float4*)(px + jb + 4);
        t2 = *(const float4*)(px + jb + 8);
        t3 = *(const float4*)(px + jb + 12);
    } else {
        LD4C(t0, jb) LD4C(t1, jb + 4) LD4C(t2, jb + 8) LD4C(t3, jb + 12)
    }
    if (nbase >= 0 && nbase + 15 < TV) {
        nb0 = *(const float4*)(px + nbase);
        nb1 = *(const float4*)(px + nbase + 4);
        nb2 = *(const float4*)(px + nbase + 8);
        nb3 = *(const float4*)(px + nbase + 12);
    } else {
        LD4C(nb0, nbase) LD4C(nb1, nbase + 4) LD4C(nb2, nbase + 8) LD4C(nb3, nbase + 12)
    }
#undef LD4C
#undef ICLAMP

    float s_p = 0.f, s_x = 0.f, s_xx = 0.f;
    ushort pk[16];
#define PROC1(XV, OV, E)                                       \
    {                                                          \
        int jtl = k * 16 + (E);                                \
        float wn = asv;                                        \
        if (eLo && jtl < VV) wn = 0.f;                         \
        if (eHi && jtl >= JT - VV) wn = 0.f;                   \
        float yv = wt * (XV) + wn * (OV);                      \
        bool valid = jtl < JT;                                 \
        yv = valid ? yv : 0.f;                                 \
        float xs = valid ? (XV) : 0.f;                         \
        s_p += yv; s_x += xs; s_xx += xs * xs;                 \
        pk[E] = f2bf(yv);                                      \
    }
    PROC1(t0.x, nb0.x, 0)  PROC1(t0.y, nb0.y, 1)  PROC1(t0.z, nb0.z, 2)  PROC1(t0.w, nb0.w, 3)
    PROC1(t1.x, nb1.x, 4)  PROC1(t1.y, nb1.y, 5)  PROC1(t1.z, nb1.z, 6)  PROC1(t1.w, nb1.w, 7)
    PROC1(t2.x, nb2.x, 8)  PROC1(t2.y, nb2.y, 9)  PROC1(t2.z, nb2.z, 10) PROC1(t2.w, nb2.w, 11)
    PROC1(t3.x, nb3.x, 12) PROC1(t3.y, nb3.y, 13) PROC1(t3.z, nb3.z, 14) PROC1(t3.w, nb3.w, 15)
#undef PROC1

    for (int o = 4; o > 0; o >>= 1) {
        s_p += __shfl_down(s_p, o, 8);
        s_x += __shfl_down(s_x, o, 8);
        s_xx += __shfl_down(s_xx, o, 8);
    }
    if (k == 0) {
        atomicAdd(&ws[OFF_PS + n * CC + c], s_p);
        atomicAdd(&ws[OFF_S1P + c * 64 + n], s_x);
        atomicAdd(&ws[OFF_SS1P + c * 64 + n], s_xx);
    }
#pragma unroll
    for (int h2 = 0; h2 < 2; ++h2) {
        uint32_t d0 = (uint32_t)pk[h2 * 8 + 0] | ((uint32_t)pk[h2 * 8 + 1] << 16);
        uint32_t d1 = (uint32_t)pk[h2 * 8 + 2] | ((uint32_t)pk[h2 * 8 + 3] << 16);
        uint32_t d2 = (uint32_t)pk[h2 * 8 + 4] | ((uint32_t)pk[h2 * 8 + 5] << 16);
        uint32_t d3 = (uint32_t)pk[h2 * 8 + 6] | ((uint32_t)pk[h2 * 8 + 7] << 16);
        int ci = 2 * k + h2;
        int m = (ci & 8) + ((ci & 7) ^ key);
        uint4 v; v.x = d0; v.y = d1; v.z = d2; v.w = d3;
        *(uint4*)&ytile[cl * 128 + m * 8] = v;
    }
    __syncthreads();

    for (int it = 0; it < 2; ++it) {
        int idx = it * 256 + tid;
        int s = idx & 3;
        int jl = idx >> 2;
        if (jl < JT) {
            int p = jl >> 6, jqv = (jl >> 3) & 7, e = jl & 7;
            uint32_t dw[4];
#pragma unroll
            for (int h = 0; h < 4; ++h) {
                int c0 = 8 * s + 2 * h, c1 = c0 + 1;
                int m0 = p * 8 + (jqv ^ (c0 & 7) ^ s);
                int m1 = p * 8 + (jqv ^ (c1 & 7) ^ s);
                ushort lo = ytile[c0 * 128 + m0 * 8 + e];
                ushort hi = ytile[c1 * 128 + m1 * 8 + e];
                dw[h] = (uint32_t)lo | ((uint32_t)hi << 16);
            }
            int jg = j0 + jl;
            int sg = ch * 4 + s;
            size_t rowb = ((size_t)n * JPAD + jg) * 128;
            *(uint4*)&yT[rowb + (size_t)((sg ^ (jg & 7)) << 3)] = *(uint4*)dw;
        }
    }
}

// wmix + absorbed gate: per-block (n) computes bn1-final + p + fc1/fc2/softmax,
// then wT'[n][d][c] = A_c*w bf16 swizzled + bias2/corr terms.
__global__ __launch_bounds__(256) void k_wmix(const float* __restrict__ g1, const float* __restrict__ b1,
                                              const float* __restrict__ fc1_w, const float* __restrict__ fc1_b,
                                              const float* __restrict__ fc2_w, const float* __restrict__ fc2_b,
                                              const int* __restrict__ epoch_p,
                                              const float* __restrict__ tw, const float* __restrict__ tb,
                                              const float* __restrict__ shift_in,
                                              float* __restrict__ ws, ushort* __restrict__ wT) {
    __shared__ float A1s[CC], B1s[CC], psh[CC], hsh[RR], gsh[4];
    int n = blockIdx.x, tid = threadIdx.x;
    if (tid < CC) {
        int c = tid;
        float s = 0.f, ss = 0.f;
        for (int g = 0; g < 64; ++g) { s += ws[OFF_S1P + c * 64 + g]; ss += ws[OFF_SS1P + c * 64 + g]; }
        const float inv = 1.f / (float)(NN * TV);
        float m = s * inv;
        float var = ss * inv - m * m;
        float A = rsqrtf(var + 1e-5f) * g1[c];
        float B = b1[c] - m * A;
        A1s[c] = A; B1s[c] = B;
        float sh = shift_in[c];
        float gb = (sh >= 0.f) ? (1.f - sh) : (1.f + sh);
        float meang = (299.f + gb) * (1.f / 300.f);
        psh[c] = A * (ws[OFF_PS + n * CC + c] * (1.f / (float)TV)) + B * meang;
    }
    __syncthreads();
    {
        int r = tid >> 3, lane8 = tid & 7;
        float acc = 0.f;
        for (int c = lane8; c < CC; c += 8) acc += psh[c] * fc1_w[r * CC + c];
        for (int o = 4; o > 0; o >>= 1) acc += __shfl_down(acc, o, 8);
        if (lane8 == 0) hsh[r] = fmaxf(acc + fc1_b[r], 0.f);
    }
    __syncthreads();
    if (tid == 0) {
        int ep = *epoch_p;
        float tao = (ep < 60) ? (-(29.f / 60.f) * (float)ep + 30.f) : 1.f;
        float li[4];
        float mx = -1e30f;
#pragma unroll
        for (int kk = 0; kk < 4; ++kk) {
            float acc = fc2_b[kk];
            for (int r = 0; r < RR; ++r) acc += hsh[r] * fc2_w[kk * RR + r];
            li[kk] = acc / tao;
            mx = fmaxf(mx, li[kk]);
        }
        float se = 0.f;
#pragma unroll
        for (int kk = 0; kk < 4; ++kk) { li[kk] = expf(li[kk] - mx); se += li[kk]; }
        float inv = 1.f / se;
#pragma unroll
        for (int kk = 0; kk < 4; ++kk) gsh[kk] = li[kk] * inv;
    }
    __syncthreads();
    int d = tid;
    float g0 = gsh[0], g1v = gsh[1], g2 = gsh[2], g3 = gsh[3];
    float bias2 = g0 * tb[d] + g1v * tb[DD + d] + g2 * tb[2 * DD + d] + g3 * tb[3 * DD + d];
    float c0acc = 0.f, c9acc = 0.f;
    ushort* wrow = wT + ((size_t)n * DD + d) * 128;
    for (int s = 0; s < 16; ++s) {
        uint32_t dw[4];
#pragma unroll
        for (int h = 0; h < 4; ++h) {
            ushort e01[2];
#pragma unroll
            for (int q = 0; q < 2; ++q) {
                int c = s * 8 + 2 * h + q;
                const float* twc = tw + (size_t)c * DD + d;
                float wv = g0 * twc[0] + g1v * twc[32768] + g2 * twc[65536] + g3 * twc[98304];
                float A = A1s[c], B = B1s[c];
                float sh = shift_in[c];
                bias2 += B * wv;
                if (sh >= 0.f) c9acc += B * sh * wv; else c0acc += B * (-sh) * wv;
                e01[q] = f2bf(A * wv);
            }
            dw[h] = (uint32_t)e01[0] | ((uint32_t)e01[1] << 16);
        }
        *(uint4*)&wrow[(s ^ (d & 7)) << 3] = *(uint4*)dw;
    }
    ws[OFF_BIAS2 + n * DD + d] = bias2;
    ws[OFF_CORR0 + n * DD + d] = c0acc;
    ws[OFF_CORR9 + n * DD + d] = c9acc;
}

// MFMA GEMM v4: swapped operands -> C row=j, col=d; direct packed dwordx2 stores.
__global__ __launch_bounds__(256, 2) void k_gemm(const ushort* __restrict__ yT,
                                                 const ushort* __restrict__ wT,
                                                 const float* __restrict__ ws,
                                                 ushort* __restrict__ zbuf) {
    __shared__ ushort yl[128 * 128];       // 32 KB
    __shared__ ushort wlb[2][64 * 128];    // 2 x 16 KB
    int jt = blockIdx.x, n = blockIdx.y;
    int tid = threadIdx.x;
    const char* ysrc = (const char*)(yT + ((size_t)n * JPAD + jt * 128) * 128);
    const char* wsrc = (const char*)(wT + (size_t)n * DD * 128);
#pragma unroll
    for (int i = 0; i < 8; ++i)
        async_copy16(ysrc + (size_t)(i * 256 + tid) * 16, (char*)yl + (i * 256 + tid) * 16);
#pragma unroll
    for (int i = 0; i < 4; ++i)
        async_copy16(wsrc + (size_t)(i * 256 + tid) * 16, (char*)wlb[0] + (i * 256 + tid) * 16);
    __syncthreads();
    int lane = tid & 63, wid = tid >> 6;
    int wj = wid >> 1, wd = wid & 1;
    int l16 = lane & 15, g = lane >> 4;
    bool edge = (jt == 0) || (jt == 58);
    short8 yfr[4][4];
#pragma unroll
    for (int ji = 0; ji < 4; ++ji)
#pragma unroll
        for (int ks = 0; ks < 4; ++ks) {
            int chunk = (ks * 4 + g) ^ (l16 & 7);
            yfr[ji][ks] = *(const short8*)&yl[(wj * 64 + ji * 16 + l16) * 128 + chunk * 8];
        }
#pragma unroll
    for (int dt = 0; dt < 4; ++dt) {
        if (dt) __syncthreads();
        if (dt < 3) {
            const char* wc = wsrc + (size_t)(dt + 1) * 16384;
#pragma unroll
            for (int i = 0; i < 4; ++i)
                async_copy16(wc + (size_t)(i * 256 + tid) * 16,
                             (char*)wlb[(dt + 1) & 1] + (i * 256 + tid) * 16);
        }
        const ushort* wcur = wlb[dt & 1];
        f32x4 acc[4][2];
#pragma unroll
        for (int a = 0; a < 4; ++a)
#pragma unroll
            for (int b = 0; b < 2; ++b) acc[a][b] = (f32x4)0.f;
#pragma unroll
        for (int ks = 0; ks < 4; ++ks) {
            short8 wf[2];
            int chunk = (ks * 4 + g) ^ (l16 & 7);
#pragma unroll
            for (int di = 0; di < 2; ++di)
                wf[di] = *(const short8*)&wcur[(wd * 32 + di * 16 + l16) * 128 + chunk * 8];
#pragma unroll
            for (int ji = 0; ji < 4; ++ji)
#pragma unroll
                for (int di = 0; di < 2; ++di)
                    acc[ji][di] = __builtin_amdgcn_mfma_f32_16x16x32_bf16(yfr[ji][ks], wf[di], acc[ji][di], 0, 0, 0);
        }
#pragma unroll
        for (int di = 0; di < 2; ++di) {
            int d = dt * 64 + wd * 32 + di * 16 + l16;
            float bias = ws[OFF_BIAS2 + n * DD + d];
            float cr0 = 0.f, cr9 = 0.f;
            if (edge) { cr0 = ws[OFF_CORR0 + n * DD + d]; cr9 = ws[OFF_CORR9 + n * DD + d]; }
            size_t zrow = ((size_t)n * DD + d) * JPAD;
#pragma unroll
            for (int ji = 0; ji < 4; ++ji) {
                int jl = wj * 64 + ji * 16 + g * 4;
                f32x4 v = acc[ji][di];
                float e0 = v[0] + bias, e1 = v[1] + bias, e2 = v[2] + bias, e3 = v[3] + bias;
                if (edge) {
                    int jg = jt * 128 + jl;
                    if (jg + 0 < VV) e0 -= cr0;  if (jg + 0 >= TV - VV) e0 -= cr9;
                    if (jg + 1 < VV) e1 -= cr0;  if (jg + 1 >= TV - VV) e1 -= cr9;
                    if (jg + 2 < VV) e2 -= cr0;  if (jg + 2 >= TV - VV) e2 -= cr9;
                    if (jg + 3 < VV) e3 -= cr0;  if (jg + 3 >= TV - VV) e3 -= cr9;
                }
                uint2 pv;
                pv.x = (uint32_t)f2bf(fmaxf(e0, 0.f)) | ((uint32_t)f2bf(fmaxf(e1, 0.f)) << 16);
                pv.y = (uint32_t)f2bf(fmaxf(e2, 0.f)) | ((uint32_t)f2bf(fmaxf(e3, 0.f)) << 16);
                *(uint2*)&zbuf[zrow + jt * 128 + jl] = pv;
            }
        }
    }
}

// streaming BN2 stats: stage z row in LDS, 2-tap shifted combine, reduce.
__global__ __launch_bounds__(256) void k_bn2_stats(const ushort* __restrict__ zbuf,
                                                   const float* __restrict__ shift_out,
                                                   float* __restrict__ ws) {
    __shared__ ushort zl[JPAD];
    int d = blockIdx.x & 255;
    int n = blockIdx.x >> 8;
    int tid = threadIdx.x;
    const char* zrow = (const char*)(zbuf + ((size_t)n * DD + d) * JPAD);
    for (int k = tid; k < JPAD / 8; k += 256)
        async_copy16(zrow + (size_t)k * 16, (char*)zl + k * 16);
    __syncthreads();
    float sh = shift_out[d];
    float alpha = (sh >= 0.f) ? (1.f - sh) : (-sh);
    float beta  = (sh >= 0.f) ? sh : (1.f + sh);
    int o25 = (sh >= 0.f) ? 0 : -25;
    float s = 0.f, ss = 0.f;
    for (int jj = tid; jj < TV; jj += 256) {
        int i0 = jj + o25, i1 = jj + o25 + 25;
        float z0 = bf2f(zl[max(i0, 0)]);
        float z1 = bf2f(zl[min(i1, TV - 1)]);
        z0 = (i0 >= 0) ? z0 : 0.f;
        z1 = (i1 < TV) ? z1 : 0.f;
        float zs = alpha * z0 + beta * z1;
        s += zs;
        ss += zs * zs;
    }
    block_reduce2(s, ss);
    if (tid == 0) {
        atomicAdd(&ws[OFF_SUM2 + d], s);
        atomicAdd(&ws[OFF_SUMSQ2 + d], ss);
    }
}

// out = shifted(z)*A2 + B2; A2/B2 derived in-block from summed stats.
__global__ __launch_bounds__(256) void k_out(const ushort* __restrict__ zbuf,
                                             const float* __restrict__ shift_out,
                                             const float* __restrict__ g2,
                                             const float* __restrict__ b2,
                                             const float* __restrict__ ws,
                                             float* __restrict__ out) {
    __shared__ ushort zl[JPAD];
    int d = blockIdx.x & 255;
    int n = blockIdx.x >> 8;
    int tid = threadIdx.x;
    const char* zrow = (const char*)(zbuf + ((size_t)n * DD + d) * JPAD);
    for (int k = tid; k < JPAD / 8; k += 256)
        async_copy16(zrow + (size_t)k * 16, (char*)zl + k * 16);
    const float inv = 1.f / (float)(NN * TV);
    float m = ws[OFF_SUM2 + d] * inv;
    float var = ws[OFF_SUMSQ2 + d] * inv - m * m;
    float rstd = rsqrtf(var + 1e-5f);
    float A = rstd * g2[d];
    float B = b2[d] - m * A;
    __syncthreads();
    float sh = shift_out[d];
    float alpha = (sh >= 0.f) ? (1.f - sh) : (-sh);
    float beta  = (sh >= 0.f) ? sh : (1.f + sh);
    int o25 = (sh >= 0.f) ? 0 : -25;
    float4* orow = (float4*)(out + ((size_t)n * DD + d) * TV);
    for (int k = tid; k < TV / 4; k += 256) {
        int jj = k * 4;
        float4 o4;
        float* op = &o4.x;
#pragma unroll
        for (int q = 0; q < 4; ++q) {
            int i0 = jj + q + o25, i1 = jj + q + o25 + 25;
            float z0 = bf2f(zl[max(i0, 0)]);
            float z1 = bf2f(zl[min(i1, TV - 1)]);
            z0 = (i0 >= 0) ? z0 : 0.f;
            z1 = (i1 < TV) ? z1 : 0.f;
            op[q] = (alpha * z0 + beta * z1) * A + B;
        }
        orow[k] = o4;
    }
}

extern "C" void kernel_launch(void* const* d_in, const int* in_sizes, int n_in,
                              void* d_out, int out_size, void* d_ws, size_t ws_size,
                              hipStream_t stream) {
    const float* x        = (const float*)d_in[0];
    const int*   epoch    = (const int*)d_in[1];
    const float* bn1_g    = (const float*)d_in[2];
    const float* bn1_b    = (const float*)d_in[3];
    const float* bn2_g    = (const float*)d_in[4];
    const float* bn2_b    = (const float*)d_in[5];
    const float* shift_in = (const float*)d_in[6];
    const float* shift_out= (const float*)d_in[7];
    const float* fc1_w    = (const float*)d_in[8];
    const float* fc1_b    = (const float*)d_in[9];
    const float* fc2_w    = (const float*)d_in[10];
    const float* fc2_b    = (const float*)d_in[11];
    const float* tw       = (const float*)d_in[12];
    const float* tb       = (const float*)d_in[13];
    float* out = (float*)d_out;
    float* ws  = (float*)d_ws;
    ushort* yT = (ushort*)d_out;                    // parked in d_out until k_out
    ushort* wT = (ushort*)((char*)d_ws + WT_BYTE_OFF);
    ushort* zb = (ushort*)((char*)d_ws + Z_BYTE_OFF);

    k_zero<<<32, 256, 0, stream>>>(ws);
    k_shift_stats<<<dim3(NJT, 4, NN), 256, 0, stream>>>(x, shift_in, ws, yT);
    k_wmix<<<64, 256, 0, stream>>>(bn1_g, bn1_b, fc1_w, fc1_b, fc2_w, fc2_b, epoch,
                                   tw, tb, shift_in, ws, wT);
    k_gemm<<<dim3(59, 64), 256, 0, stream>>>(yT, wT, ws, zb);
    k_bn2_stats<<<16384, 256, 0, stream>>>(zb, shift_out, ws);
    k_out<<<16384, 256, 0, stream>>>(zb, shift_out, bn2_g, bn2_b, ws, out);
}

// Round 13
// 433.868 us; speedup vs baseline: 1.1543x; 1.1543x over previous
//
#include <hip/hip_runtime.h>
#include <stdint.h>

#define NN 64
#define CC 128
#define TT 300
#define VV 25
#define TV 7500
#define DD 256
#define RR 32
#define JPAD 7552   // padded row stride for yT and z (59*128)
#define JT 125      // shift kernel j-tile (exactly 5 t-columns)
#define NJT 60
#define XSTR 181    // xw float stride per c-row (odd -> 4-way-max banks)
#define CBL 32      // c per shift block

// ws float offsets
#define OFF_S1P    0          // [c][64] partial x sums
#define OFF_SS1P   8192       // [c][64] partial x sumsq
#define OFF_PS     16384      // [n][c] xs sums
#define OFF_SUM2   24832
#define OFF_SUMSQ2 25088
#define OFF_GATE   25856
#define OFF_BIAS2  26112      // [n][d]
#define OFF_CORR0  42496      // [n][d]
#define OFF_CORR9  58880      // [n][d]
#define FLOAT_REGION 75264
#define ZERO_CNT   25344
#define WT_BYTE_OFF ((size_t)FLOAT_REGION * 4)
#define WT_BYTES    ((size_t)NN * DD * CC * 2)
#define Z_BYTE_OFF  (WT_BYTE_OFF + WT_BYTES)

typedef __attribute__((ext_vector_type(8))) short short8;
typedef __attribute__((ext_vector_type(4))) float f32x4;

typedef const __attribute__((address_space(1))) uint32_t gas_u32;
typedef __attribute__((address_space(3))) uint32_t las_u32;

__device__ inline ushort f2bf(float f) {
    uint32_t u = __float_as_uint(f);
    u += 0x7fffu + ((u >> 16) & 1u);
    return (ushort)(u >> 16);
}
__device__ inline float bf2f(ushort v) { return __uint_as_float(((uint32_t)v) << 16); }
__device__ inline void async_copy16(const void* g, void* l) {
    __builtin_amdgcn_global_load_lds((gas_u32*)g, (las_u32*)l, 16, 0, 0);
}

__device__ inline void block_reduce2(float& a, float& b) {
    __shared__ float sa[4], sb[4];
    for (int off = 32; off > 0; off >>= 1) {
        a += __shfl_down(a, off);
        b += __shfl_down(b, off);
    }
    int lane = threadIdx.x & 63, wid = threadIdx.x >> 6;
    if (lane == 0) { sa[wid] = a; sb[wid] = b; }
    __syncthreads();
    if (threadIdx.x == 0) {
        a = sa[0] + sa[1] + sa[2] + sa[3];
        b = sb[0] + sb[1] + sb[2] + sb[3];
    }
}

__global__ void k_zero(float* ws) {
    int i = blockIdx.x * 256 + threadIdx.x;
    for (; i < ZERO_CNT; i += 32 * 256) ws[i] = 0.f;
}

// Shift+stats v3: linear-tap algebra, odd-stride LDS window. grid (60, 4, 64).
__global__ __launch_bounds__(256) void k_shift_stats(const float* __restrict__ x,
                                                     const float* __restrict__ shift_in,
                                                     float* __restrict__ ws,
                                                     ushort* __restrict__ yT) {
    __shared__ float  xw[CBL * XSTR];     // 23168 B
    __shared__ ushort ytile[CBL * 128];   // 8192 B
    int jt = blockIdx.x, ch = blockIdx.y, n = blockIdx.z;
    int j0 = jt * JT;
    int t0 = jt * 5;
    int t_lo = max(t0 - 1, 0);
    int start_f = (t_lo * VV) & ~3;
    int doff = t_lo * VV - start_f;
    int tid = threadIdx.x;
    int lane = tid & 63, w = tid >> 6;
    int nvalid = min(45, (TV - start_f) >> 2);

    const float* xbase = x + ((size_t)n * CC + ch * CBL) * TV;
#pragma unroll
    for (int rr = 0; rr < 8; ++rr) {
        int cl = w * 8 + rr;
        if (lane < nvalid) {
            float4 u = *(const float4*)(xbase + (size_t)cl * TV + start_f + lane * 4);
            int b = cl * XSTR + lane * 4;
            xw[b] = u.x; xw[b + 1] = u.y; xw[b + 2] = u.z; xw[b + 3] = u.w;
        }
    }
    __syncthreads();

    int k = tid & 7;        // thread within c: j = k*16 .. k*16+15
    int cl = tid >> 3;      // local c 0..31
    int c = ch * CBL + cl;
    float sh = shift_in[c];
    bool posi = (sh >= 0.f);
    float asv = fabsf(sh);
    float wt = 1.f - asv;
    const float* xrow = &xw[cl * XSTR];
    int tapK = (t0 - t_lo) * VV + doff;
    int ntK  = posi ? (tapK + VV) : (tapK - VV);
    int wmax = (jt == NJT - 1) ? (TV - start_f - 1) : (7 * VV + doff - 1);
    bool eLo = (jt == 0) && !posi;
    bool eHi = (jt == NJT - 1) && posi;
    int key = (cl & 7) ^ ((cl >> 3) & 7);
    float s_p = 0.f, s_x = 0.f, s_xx = 0.f;
    int jbase = k * 16;
    ushort pk[16];
#pragma unroll
    for (int e = 0; e < 16; ++e) {
        int jtl = jbase + e;
        int ja = min(jtl, JT - 1);
        float xv = xrow[ja + tapK];
        int np = min(max(ja + ntK, 0), wmax);
        float ot = xrow[np];
        float wn = asv;
        if (eLo && jtl < VV) wn = 0.f;
        if (eHi && jtl >= JT - VV) wn = 0.f;
        float yv = wt * xv + wn * ot;
        bool valid = jtl < JT;
        yv = valid ? yv : 0.f;
        float xs = valid ? xv : 0.f;
        s_p += yv; s_x += xs; s_xx += xs * xs;
        pk[e] = f2bf(yv);
    }
    for (int off = 4; off > 0; off >>= 1) {
        s_p += __shfl_down(s_p, off, 8);
        s_x += __shfl_down(s_x, off, 8);
        s_xx += __shfl_down(s_xx, off, 8);
    }
    if (k == 0) {
        atomicAdd(&ws[OFF_PS + n * CC + c], s_p);
        atomicAdd(&ws[OFF_S1P + c * 64 + n], s_x);
        atomicAdd(&ws[OFF_SS1P + c * 64 + n], s_xx);
    }
#pragma unroll
    for (int h2 = 0; h2 < 2; ++h2) {
        uint32_t d0 = (uint32_t)pk[h2 * 8 + 0] | ((uint32_t)pk[h2 * 8 + 1] << 16);
        uint32_t d1 = (uint32_t)pk[h2 * 8 + 2] | ((uint32_t)pk[h2 * 8 + 3] << 16);
        uint32_t d2 = (uint32_t)pk[h2 * 8 + 4] | ((uint32_t)pk[h2 * 8 + 5] << 16);
        uint32_t d3 = (uint32_t)pk[h2 * 8 + 6] | ((uint32_t)pk[h2 * 8 + 7] << 16);
        int ci = 2 * k + h2;
        int m = (ci & 8) + ((ci & 7) ^ key);
        uint4 v; v.x = d0; v.y = d1; v.z = d2; v.w = d3;
        *(uint4*)&ytile[cl * 128 + m * 8] = v;
    }
    __syncthreads();

    for (int it = 0; it < 2; ++it) {
        int idx = it * 256 + tid;
        int s = idx & 3;
        int jl = idx >> 2;
        if (jl < JT) {
            int p = jl >> 6, jqv = (jl >> 3) & 7, e = jl & 7;
            uint32_t dw[4];
#pragma unroll
            for (int h = 0; h < 4; ++h) {
                int c0 = 8 * s + 2 * h, c1 = c0 + 1;
                int m0 = p * 8 + (jqv ^ (c0 & 7) ^ s);
                int m1 = p * 8 + (jqv ^ (c1 & 7) ^ s);
                ushort lo = ytile[c0 * 128 + m0 * 8 + e];
                ushort hi = ytile[c1 * 128 + m1 * 8 + e];
                dw[h] = (uint32_t)lo | ((uint32_t)hi << 16);
            }
            int jg = j0 + jl;
            int sg = ch * 4 + s;
            size_t rowb = ((size_t)n * JPAD + jg) * 128;
            *(uint4*)&yT[rowb + (size_t)((sg ^ (jg & 7)) << 3)] = *(uint4*)dw;
        }
    }
}

// wmix + absorbed gate: per-block (n) computes bn1-final + p + fc1/fc2/softmax,
// then wT'[n][d][c] = A_c*w bf16 swizzled + bias2/corr terms.
__global__ __launch_bounds__(256) void k_wmix(const float* __restrict__ g1, const float* __restrict__ b1,
                                              const float* __restrict__ fc1_w, const float* __restrict__ fc1_b,
                                              const float* __restrict__ fc2_w, const float* __restrict__ fc2_b,
                                              const int* __restrict__ epoch_p,
                                              const float* __restrict__ tw, const float* __restrict__ tb,
                                              const float* __restrict__ shift_in,
                                              float* __restrict__ ws, ushort* __restrict__ wT) {
    __shared__ float A1s[CC], B1s[CC], psh[CC], hsh[RR], gsh[4];
    int n = blockIdx.x, tid = threadIdx.x;
    if (tid < CC) {
        int c = tid;
        float s = 0.f, ss = 0.f;
        for (int g = 0; g < 64; ++g) { s += ws[OFF_S1P + c * 64 + g]; ss += ws[OFF_SS1P + c * 64 + g]; }
        const float inv = 1.f / (float)(NN * TV);
        float m = s * inv;
        float var = ss * inv - m * m;
        float A = rsqrtf(var + 1e-5f) * g1[c];
        float B = b1[c] - m * A;
        A1s[c] = A; B1s[c] = B;
        float sh = shift_in[c];
        float gb = (sh >= 0.f) ? (1.f - sh) : (1.f + sh);
        float meang = (299.f + gb) * (1.f / 300.f);
        psh[c] = A * (ws[OFF_PS + n * CC + c] * (1.f / (float)TV)) + B * meang;
    }
    __syncthreads();
    {
        int r = tid >> 3, lane8 = tid & 7;
        float acc = 0.f;
        for (int c = lane8; c < CC; c += 8) acc += psh[c] * fc1_w[r * CC + c];
        for (int o = 4; o > 0; o >>= 1) acc += __shfl_down(acc, o, 8);
        if (lane8 == 0) hsh[r] = fmaxf(acc + fc1_b[r], 0.f);
    }
    __syncthreads();
    if (tid == 0) {
        int ep = *epoch_p;
        float tao = (ep < 60) ? (-(29.f / 60.f) * (float)ep + 30.f) : 1.f;
        float li[4];
        float mx = -1e30f;
#pragma unroll
        for (int kk = 0; kk < 4; ++kk) {
            float acc = fc2_b[kk];
            for (int r = 0; r < RR; ++r) acc += hsh[r] * fc2_w[kk * RR + r];
            li[kk] = acc / tao;
            mx = fmaxf(mx, li[kk]);
        }
        float se = 0.f;
#pragma unroll
        for (int kk = 0; kk < 4; ++kk) { li[kk] = expf(li[kk] - mx); se += li[kk]; }
        float inv = 1.f / se;
#pragma unroll
        for (int kk = 0; kk < 4; ++kk) gsh[kk] = li[kk] * inv;
    }
    __syncthreads();
    int d = tid;
    float g0 = gsh[0], g1v = gsh[1], g2 = gsh[2], g3 = gsh[3];
    float bias2 = g0 * tb[d] + g1v * tb[DD + d] + g2 * tb[2 * DD + d] + g3 * tb[3 * DD + d];
    float c0acc = 0.f, c9acc = 0.f;
    ushort* wrow = wT + ((size_t)n * DD + d) * 128;
    for (int s = 0; s < 16; ++s) {
        uint32_t dw[4];
#pragma unroll
        for (int h = 0; h < 4; ++h) {
            ushort e01[2];
#pragma unroll
            for (int q = 0; q < 2; ++q) {
                int c = s * 8 + 2 * h + q;
                const float* twc = tw + (size_t)c * DD + d;
                float wv = g0 * twc[0] + g1v * twc[32768] + g2 * twc[65536] + g3 * twc[98304];
                float A = A1s[c], B = B1s[c];
                float sh = shift_in[c];
                bias2 += B * wv;
                if (sh >= 0.f) c9acc += B * sh * wv; else c0acc += B * (-sh) * wv;
                e01[q] = f2bf(A * wv);
            }
            dw[h] = (uint32_t)e01[0] | ((uint32_t)e01[1] << 16);
        }
        *(uint4*)&wrow[(s ^ (d & 7)) << 3] = *(uint4*)dw;
    }
    ws[OFF_BIAS2 + n * DD + d] = bias2;
    ws[OFF_CORR0 + n * DD + d] = c0acc;
    ws[OFF_CORR9 + n * DD + d] = c9acc;
}

// MFMA GEMM v4: swapped operands -> C row=j, col=d; direct packed dwordx2 stores.
__global__ __launch_bounds__(256, 2) void k_gemm(const ushort* __restrict__ yT,
                                                 const ushort* __restrict__ wT,
                                                 const float* __restrict__ ws,
                                                 ushort* __restrict__ zbuf) {
    __shared__ ushort yl[128 * 128];       // 32 KB
    __shared__ ushort wlb[2][64 * 128];    // 2 x 16 KB
    int jt = blockIdx.x, n = blockIdx.y;
    int tid = threadIdx.x;
    const char* ysrc = (const char*)(yT + ((size_t)n * JPAD + jt * 128) * 128);
    const char* wsrc = (const char*)(wT + (size_t)n * DD * 128);
#pragma unroll
    for (int i = 0; i < 8; ++i)
        async_copy16(ysrc + (size_t)(i * 256 + tid) * 16, (char*)yl + (i * 256 + tid) * 16);
#pragma unroll
    for (int i = 0; i < 4; ++i)
        async_copy16(wsrc + (size_t)(i * 256 + tid) * 16, (char*)wlb[0] + (i * 256 + tid) * 16);
    __syncthreads();
    int lane = tid & 63, wid = tid >> 6;
    int wj = wid >> 1, wd = wid & 1;
    int l16 = lane & 15, g = lane >> 4;
    bool edge = (jt == 0) || (jt == 58);
    short8 yfr[4][4];
#pragma unroll
    for (int ji = 0; ji < 4; ++ji)
#pragma unroll
        for (int ks = 0; ks < 4; ++ks) {
            int chunk = (ks * 4 + g) ^ (l16 & 7);
            yfr[ji][ks] = *(const short8*)&yl[(wj * 64 + ji * 16 + l16) * 128 + chunk * 8];
        }
#pragma unroll
    for (int dt = 0; dt < 4; ++dt) {
        if (dt) __syncthreads();
        if (dt < 3) {
            const char* wc = wsrc + (size_t)(dt + 1) * 16384;
#pragma unroll
            for (int i = 0; i < 4; ++i)
                async_copy16(wc + (size_t)(i * 256 + tid) * 16,
                             (char*)wlb[(dt + 1) & 1] + (i * 256 + tid) * 16);
        }
        const ushort* wcur = wlb[dt & 1];
        f32x4 acc[4][2];
#pragma unroll
        for (int a = 0; a < 4; ++a)
#pragma unroll
            for (int b = 0; b < 2; ++b) acc[a][b] = (f32x4)0.f;
#pragma unroll
        for (int ks = 0; ks < 4; ++ks) {
            short8 wf[2];
            int chunk = (ks * 4 + g) ^ (l16 & 7);
#pragma unroll
            for (int di = 0; di < 2; ++di)
                wf[di] = *(const short8*)&wcur[(wd * 32 + di * 16 + l16) * 128 + chunk * 8];
#pragma unroll
            for (int ji = 0; ji < 4; ++ji)
#pragma unroll
                for (int di = 0; di < 2; ++di)
                    acc[ji][di] = __builtin_amdgcn_mfma_f32_16x16x32_bf16(yfr[ji][ks], wf[di], acc[ji][di], 0, 0, 0);
        }
#pragma unroll
        for (int di = 0; di < 2; ++di) {
            int d = dt * 64 + wd * 32 + di * 16 + l16;
            float bias = ws[OFF_BIAS2 + n * DD + d];
            float cr0 = 0.f, cr9 = 0.f;
            if (edge) { cr0 = ws[OFF_CORR0 + n * DD + d]; cr9 = ws[OFF_CORR9 + n * DD + d]; }
            size_t zrow = ((size_t)n * DD + d) * JPAD;
#pragma unroll
            for (int ji = 0; ji < 4; ++ji) {
                int jl = wj * 64 + ji * 16 + g * 4;
                f32x4 v = acc[ji][di];
                float e0 = v[0] + bias, e1 = v[1] + bias, e2 = v[2] + bias, e3 = v[3] + bias;
                if (edge) {
                    int jg = jt * 128 + jl;
                    if (jg + 0 < VV) e0 -= cr0;  if (jg + 0 >= TV - VV) e0 -= cr9;
                    if (jg + 1 < VV) e1 -= cr0;  if (jg + 1 >= TV - VV) e1 -= cr9;
                    if (jg + 2 < VV) e2 -= cr0;  if (jg + 2 >= TV - VV) e2 -= cr9;
                    if (jg + 3 < VV) e3 -= cr0;  if (jg + 3 >= TV - VV) e3 -= cr9;
                }
                uint2 pv;
                pv.x = (uint32_t)f2bf(fmaxf(e0, 0.f)) | ((uint32_t)f2bf(fmaxf(e1, 0.f)) << 16);
                pv.y = (uint32_t)f2bf(fmaxf(e2, 0.f)) | ((uint32_t)f2bf(fmaxf(e3, 0.f)) << 16);
                *(uint2*)&zbuf[zrow + jt * 128 + jl] = pv;
            }
        }
    }
}

// streaming BN2 stats: stage z row in LDS, 2-tap shifted combine, reduce.
__global__ __launch_bounds__(256) void k_bn2_stats(const ushort* __restrict__ zbuf,
                                                   const float* __restrict__ shift_out,
                                                   float* __restrict__ ws) {
    __shared__ ushort zl[JPAD];
    int d = blockIdx.x & 255;
    int n = blockIdx.x >> 8;
    int tid = threadIdx.x;
    const char* zrow = (const char*)(zbuf + ((size_t)n * DD + d) * JPAD);
    for (int k = tid; k < JPAD / 8; k += 256)
        async_copy16(zrow + (size_t)k * 16, (char*)zl + k * 16);
    __syncthreads();
    float sh = shift_out[d];
    float alpha = (sh >= 0.f) ? (1.f - sh) : (-sh);
    float beta  = (sh >= 0.f) ? sh : (1.f + sh);
    int o25 = (sh >= 0.f) ? 0 : -25;
    float s = 0.f, ss = 0.f;
    for (int jj = tid; jj < TV; jj += 256) {
        int i0 = jj + o25, i1 = jj + o25 + 25;
        float z0 = bf2f(zl[max(i0, 0)]);
        float z1 = bf2f(zl[min(i1, TV - 1)]);
        z0 = (i0 >= 0) ? z0 : 0.f;
        z1 = (i1 < TV) ? z1 : 0.f;
        float zs = alpha * z0 + beta * z1;
        s += zs;
        ss += zs * zs;
    }
    block_reduce2(s, ss);
    if (tid == 0) {
        atomicAdd(&ws[OFF_SUM2 + d], s);
        atomicAdd(&ws[OFF_SUMSQ2 + d], ss);
    }
}

// out = shifted(z)*A2 + B2; A2/B2 derived in-block from summed stats.
__global__ __launch_bounds__(256) void k_out(const ushort* __restrict__ zbuf,
                                             const float* __restrict__ shift_out,
                                             const float* __restrict__ g2,
                                             const float* __restrict__ b2,
                                             const float* __restrict__ ws,
                                             float* __restrict__ out) {
    __shared__ ushort zl[JPAD];
    int d = blockIdx.x & 255;
    int n = blockIdx.x >> 8;
    int tid = threadIdx.x;
    const char* zrow = (const char*)(zbuf + ((size_t)n * DD + d) * JPAD);
    for (int k = tid; k < JPAD / 8; k += 256)
        async_copy16(zrow + (size_t)k * 16, (char*)zl + k * 16);
    const float inv = 1.f / (float)(NN * TV);
    float m = ws[OFF_SUM2 + d] * inv;
    float var = ws[OFF_SUMSQ2 + d] * inv - m * m;
    float rstd = rsqrtf(var + 1e-5f);
    float A = rstd * g2[d];
    float B = b2[d] - m * A;
    __syncthreads();
    float sh = shift_out[d];
    float alpha = (sh >= 0.f) ? (1.f - sh) : (-sh);
    float beta  = (sh >= 0.f) ? sh : (1.f + sh);
    int o25 = (sh >= 0.f) ? 0 : -25;
    float4* orow = (float4*)(out + ((size_t)n * DD + d) * TV);
    for (int k = tid; k < TV / 4; k += 256) {
        int jj = k * 4;
        float4 o4;
        float* op = &o4.x;
#pragma unroll
        for (int q = 0; q < 4; ++q) {
            int i0 = jj + q + o25, i1 = jj + q + o25 + 25;
            float z0 = bf2f(zl[max(i0, 0)]);
            float z1 = bf2f(zl[min(i1, TV - 1)]);
            z0 = (i0 >= 0) ? z0 : 0.f;
            z1 = (i1 < TV) ? z1 : 0.f;
            op[q] = (alpha * z0 + beta * z1) * A + B;
        }
        orow[k] = o4;
    }
}

extern "C" void kernel_launch(void* const* d_in, const int* in_sizes, int n_in,
                              void* d_out, int out_size, void* d_ws, size_t ws_size,
                              hipStream_t stream) {
    const float* x        = (const float*)d_in[0];
    const int*   epoch    = (const int*)d_in[1];
    const float* bn1_g    = (const float*)d_in[2];
    const float* bn1_b    = (const float*)d_in[3];
    const float* bn2_g    = (const float*)d_in[4];
    const float* bn2_b    = (const float*)d_in[5];
    const float* shift_in = (const float*)d_in[6];
    const float* shift_out= (const float*)d_in[7];
    const float* fc1_w    = (const float*)d_in[8];
    const float* fc1_b    = (const float*)d_in[9];
    const float* fc2_w    = (const float*)d_in[10];
    const float* fc2_b    = (const float*)d_in[11];
    const float* tw       = (const float*)d_in[12];
    const float* tb       = (const float*)d_in[13];
    float* out = (float*)d_out;
    float* ws  = (float*)d_ws;
    ushort* yT = (ushort*)d_out;                    // parked in d_out until k_out
    ushort* wT = (ushort*)((char*)d_ws + WT_BYTE_OFF);
    ushort* zb = (ushort*)((char*)d_ws + Z_BYTE_OFF);

    k_zero<<<32, 256, 0, stream>>>(ws);
    k_shift_stats<<<dim3(NJT, 4, NN), 256, 0, stream>>>(x, shift_in, ws, yT);
    k_wmix<<<64, 256, 0, stream>>>(bn1_g, bn1_b, fc1_w, fc1_b, fc2_w, fc2_b, epoch,
                                   tw, tb, shift_in, ws, wT);
    k_gemm<<<dim3(59, 64), 256, 0, stream>>>(yT, wT, ws, zb);
    k_bn2_stats<<<16384, 256, 0, stream>>>(zb, shift_out, ws);
    k_out<<<16384, 256, 0, stream>>>(zb, shift_out, bn2_g, bn2_b, ws, out);
}